// Round 3
// baseline (177.260 us; speedup 1.0000x reference)
//
#include <hip/hip_runtime.h>

// B=128, A=512, N=256.
// out[b,a,n] = r_ij[b,a,n] + f(zi, zj), f has only 89*89 distinct values.
// R3: latency attack. 2 rows/wave/iter + depth-1 register prefetch
//     => 8 outstanding 16B VMEM reqs/wave (was ~2). Plain loads (no nt),
//     nt store. Same f16 LDS table (built once into d_ws), 8 blocks/CU.

#define BB 128
#define AA 512
#define NN 256
#define ROWS 32            // a-rows per block -> grid = 2048
#define TPB 256
#define TABN 8192          // 90*90=8100 rounded up for clean 16B-vector copy

typedef int   v4i __attribute__((ext_vector_type(4)));
typedef float v4f __attribute__((ext_vector_type(4)));

__device__ __forceinline__ float tab_entry(int idx) {
    int zi = idx / 90, zj = idx - zi * 90;
    float p = fmaxf((float)(zi * zj), 1.0f);
    float s = fmaxf((float)(zi + zj), 1.0f);
    const float c = -0.05f * 2.718281828459045f;
    return __expf(c * __powf(p, 1.01f) / __powf(s, 1.1f));
}

__global__ void RAN_72567767433723_build_tab(_Float16* __restrict__ tabg) {
    int idx = blockIdx.x * blockDim.x + threadIdx.x;
    tabg[idx] = (_Float16)tab_entry(idx);
}

template <bool LOAD_TAB>
__global__ __launch_bounds__(TPB, 8) void RAN_72567767433723_kernel(
    const float* __restrict__ an,
    const int*   __restrict__ nbrs,
    const float* __restrict__ rij,
    float*       __restrict__ out,
    const _Float16* __restrict__ tabg)
{
    __shared__ _Float16       tab[TABN];  // 16384 B
    __shared__ unsigned short zz[AA];     //  1024 B -> 17408 B => 8 blk/CU

    const int tid      = threadIdx.x;
    const int b        = blockIdx.x >> 4;            // 16 blocks per batch
    const int row_base = (blockIdx.x & 15) * ROWS;

    if (LOAD_TAB) {
        #pragma unroll
        for (int i = 0; i < TABN * 2 / (16 * TPB); ++i) {  // 4 iters, 16B/lane
            int k = i * TPB + tid;
            ((v4i*)tab)[k] = ((const v4i*)tabg)[k];
        }
    } else {
        for (int idx = tid; idx < TABN; idx += TPB)
            tab[idx] = (_Float16)tab_entry(idx);
    }
    #pragma unroll
    for (int i = tid; i < AA; i += TPB)
        zz[i] = (unsigned short)(int)(an[b * AA + i] + 0.5f);
    __syncthreads();

    const int w = tid >> 6;              // wave id 0..3
    const int l = tid & 63;              // float4 slot in row (N/4 = 64)
    const int r0 = row_base + w * 2;     // this wave's first row (rows r0, r0+1; +8 per iter)
    const size_t base = ((size_t)(b * AA + r0)) * NN + (size_t)(l * 4);

    // Pipeline prologue: iteration 0's four independent loads.
    v4i nbA = *(const v4i*)(nbrs + base);
    v4i nbB = *(const v4i*)(nbrs + base + NN);
    v4f rjA = *(const v4f*)(rij + base);
    v4f rjB = *(const v4f*)(rij + base + NN);

    #pragma unroll
    for (int it = 0; it < ROWS / 8; ++it) {          // 4 iterations
        const size_t e = base + (size_t)(it * 8) * NN;

        v4i nbA2, nbB2; v4f rjA2, rjB2;
        if (it < ROWS / 8 - 1) {                     // prefetch next iteration
            const size_t en = e + (size_t)(8 * NN);
            nbA2 = *(const v4i*)(nbrs + en);
            nbB2 = *(const v4i*)(nbrs + en + NN);
            rjA2 = *(const v4f*)(rij + en);
            rjB2 = *(const v4f*)(rij + en + NN);
        }

        const int a0 = r0 + it * 8;
        const int t0 = (int)zz[a0] * 90;             // wave-uniform broadcasts
        const int t1 = (int)zz[a0 + 1] * 90;

        v4f o0, o1;
        o0.x = rjA.x + (float)tab[t0 + (int)zz[nbA.x]];
        o0.y = rjA.y + (float)tab[t0 + (int)zz[nbA.y]];
        o0.z = rjA.z + (float)tab[t0 + (int)zz[nbA.z]];
        o0.w = rjA.w + (float)tab[t0 + (int)zz[nbA.w]];
        o1.x = rjB.x + (float)tab[t1 + (int)zz[nbB.x]];
        o1.y = rjB.y + (float)tab[t1 + (int)zz[nbB.y]];
        o1.z = rjB.z + (float)tab[t1 + (int)zz[nbB.z]];
        o1.w = rjB.w + (float)tab[t1 + (int)zz[nbB.w]];

        __builtin_nontemporal_store(o0, (v4f*)(out + e));
        __builtin_nontemporal_store(o1, (v4f*)(out + e + NN));

        nbA = nbA2; nbB = nbB2; rjA = rjA2; rjB = rjB2;
    }
}

extern "C" void kernel_launch(void* const* d_in, const int* in_sizes, int n_in,
                              void* d_out, int out_size, void* d_ws, size_t ws_size,
                              hipStream_t stream) {
    const float* an  = (const float*)d_in[0];
    const int*   nbr = (const int*)d_in[1];
    const float* rij = (const float*)d_in[2];
    float*       o   = (float*)d_out;

    const int grid = (BB * AA) / ROWS;   // 2048

    if (ws_size >= (size_t)TABN * sizeof(_Float16)) {
        _Float16* tabg = (_Float16*)d_ws;
        RAN_72567767433723_build_tab<<<TABN / TPB, TPB, 0, stream>>>(tabg);
        RAN_72567767433723_kernel<true><<<grid, TPB, 0, stream>>>(an, nbr, rij, o, tabg);
    } else {
        RAN_72567767433723_kernel<false><<<grid, TPB, 0, stream>>>(an, nbr, rij, o, nullptr);
    }
}

// Round 4
// 165.087 us; speedup vs baseline: 1.0737x; 1.0737x over previous
//
#include <hip/hip_runtime.h>

// B=128, A=512, N=256.
// out[b,a,n] = r_ij[b,a,n] + f(zi, zj), f has only 89*89 distinct values.
// R4: revert to R2 structure (straight-line, nt loads/stores), then raise MLP:
//     __launch_bounds__(256,4) -> 128-VGPR budget, and issue ALL 16 global
//     loads (8 iters x {nbrs,rij}) before any LDS-dependent use, so each wave
//     exposes ~one HBM latency instead of eight. R3's branchy register
//     pipeline (VGPR=24 => compiler discarded it) is abandoned.

#define BB 128
#define AA 512
#define NN 256
#define ROWS 32            // a-rows per block -> grid = 2048
#define TPB 256
#define TABN 8192          // 90*90=8100 rounded up for clean 16B-vector copy

typedef int   v4i __attribute__((ext_vector_type(4)));
typedef float v4f __attribute__((ext_vector_type(4)));

__device__ __forceinline__ float tab_entry(int idx) {
    int zi = idx / 90, zj = idx - zi * 90;
    float p = fmaxf((float)(zi * zj), 1.0f);
    float s = fmaxf((float)(zi + zj), 1.0f);
    const float c = -0.05f * 2.718281828459045f;
    return __expf(c * __powf(p, 1.01f) / __powf(s, 1.1f));
}

__global__ void RAN_72567767433723_build_tab(_Float16* __restrict__ tabg) {
    int idx = blockIdx.x * blockDim.x + threadIdx.x;
    tabg[idx] = (_Float16)tab_entry(idx);
}

template <bool LOAD_TAB>
__global__ __launch_bounds__(TPB, 4) void RAN_72567767433723_kernel(
    const float* __restrict__ an,
    const int*   __restrict__ nbrs,
    const float* __restrict__ rij,
    float*       __restrict__ out,
    const _Float16* __restrict__ tabg)
{
    __shared__ _Float16       tab[TABN];  // 16384 B
    __shared__ unsigned short zz[AA];     //  1024 B -> 17408 B total

    const int tid      = threadIdx.x;
    const int b        = blockIdx.x >> 4;            // 16 blocks per batch
    const int row_base = (blockIdx.x & 15) * ROWS;

    if (LOAD_TAB) {
        #pragma unroll
        for (int i = 0; i < TABN * 2 / (16 * TPB); ++i) {  // 4 iters, 16B/lane
            int k = i * TPB + tid;
            ((v4i*)tab)[k] = ((const v4i*)tabg)[k];
        }
    } else {
        for (int idx = tid; idx < TABN; idx += TPB)
            tab[idx] = (_Float16)tab_entry(idx);
    }
    #pragma unroll
    for (int i = tid; i < AA; i += TPB)
        zz[i] = (unsigned short)(int)(an[b * AA + i] + 0.5f);
    __syncthreads();

    const int w  = tid >> 6;             // wave id 0..3
    const int l  = tid & 63;             // float4 slot in row (N/4 = 64)
    const int a0 = row_base + w;         // wave w: rows a0 + 4*it, it=0..7
    const size_t base = ((size_t)(b * AA + a0)) * NN + (size_t)(l * 4);

    // Phase 1: issue ALL global loads (16 x 16B/lane in flight).
    v4i nb[8]; v4f rj[8];
    #pragma unroll
    for (int it = 0; it < 8; ++it) {
        const size_t e = base + (size_t)(it * 4) * NN;
        nb[it] = __builtin_nontemporal_load((const v4i*)(nbrs + e));
        rj[it] = __builtin_nontemporal_load((const v4f*)(rij + e));
    }

    // Row-base table offsets (wave-uniform LDS broadcasts).
    int tb[8];
    #pragma unroll
    for (int it = 0; it < 8; ++it)
        tb[it] = (int)zz[a0 + it * 4] * 90;

    // Phase 2: LDS gathers + stores, consuming loads in issue order.
    #pragma unroll
    for (int it = 0; it < 8; ++it) {
        const size_t e = base + (size_t)(it * 4) * NN;
        v4f o;
        o.x = rj[it].x + (float)tab[tb[it] + (int)zz[nb[it].x]];
        o.y = rj[it].y + (float)tab[tb[it] + (int)zz[nb[it].y]];
        o.z = rj[it].z + (float)tab[tb[it] + (int)zz[nb[it].z]];
        o.w = rj[it].w + (float)tab[tb[it] + (int)zz[nb[it].w]];
        __builtin_nontemporal_store(o, (v4f*)(out + e));
    }
}

extern "C" void kernel_launch(void* const* d_in, const int* in_sizes, int n_in,
                              void* d_out, int out_size, void* d_ws, size_t ws_size,
                              hipStream_t stream) {
    const float* an  = (const float*)d_in[0];
    const int*   nbr = (const int*)d_in[1];
    const float* rij = (const float*)d_in[2];
    float*       o   = (float*)d_out;

    const int grid = (BB * AA) / ROWS;   // 2048

    if (ws_size >= (size_t)TABN * sizeof(_Float16)) {
        _Float16* tabg = (_Float16*)d_ws;
        RAN_72567767433723_build_tab<<<TABN / TPB, TPB, 0, stream>>>(tabg);
        RAN_72567767433723_kernel<true><<<grid, TPB, 0, stream>>>(an, nbr, rij, o, tabg);
    } else {
        RAN_72567767433723_kernel<false><<<grid, TPB, 0, stream>>>(an, nbr, rij, o, nullptr);
    }
}